// Round 2
// baseline (504.209 us; speedup 1.0000x reference)
//
#include <hip/hip_runtime.h>

#define DEG_CAP 64

__device__ __forceinline__ int rfl(int v) { return __builtin_amdgcn_readfirstlane(v); }

// ---------- edge MLP layer 1: he[E,16] = relu(ea @ w_e1 + b_e1) ----------
__global__ void k_he(const float* __restrict__ ea, const float* __restrict__ w,
                     const float* __restrict__ b, float* __restrict__ he, int E) {
  int e = blockIdx.x * blockDim.x + threadIdx.x;
  if (e >= E) return;
  const float4* eap = reinterpret_cast<const float4*>(ea + (size_t)e * 8);
  float4 a0 = eap[0], a1 = eap[1];
  float av[8] = {a0.x, a0.y, a0.z, a0.w, a1.x, a1.y, a1.z, a1.w};
  float o[16];
#pragma unroll
  for (int k = 0; k < 16; ++k) o[k] = b[k];
#pragma unroll
  for (int t = 0; t < 8; ++t) {
    float at = av[t];
#pragma unroll
    for (int k = 0; k < 16; ++k) o[k] = fmaf(at, w[t * 16 + k], o[k]);
  }
#pragma unroll
  for (int k = 0; k < 16; ++k) o[k] = fmaxf(o[k], 0.f);
  float4* hp = reinterpret_cast<float4*>(he + (size_t)e * 16);
  hp[0] = make_float4(o[0], o[1], o[2], o[3]);
  hp[1] = make_float4(o[4], o[5], o[6], o[7]);
  hp[2] = make_float4(o[8], o[9], o[10], o[11]);
  hp[3] = make_float4(o[12], o[13], o[14], o[15]);
}

// ---------- build capped CSR-by-dst ----------
__global__ void k_fill(const int* __restrict__ ei, int* __restrict__ cursor,
                       int* __restrict__ slots, int E) {
  int e = blockIdx.x * blockDim.x + threadIdx.x;
  if (e >= E) return;
  int dst = ei[E + e];
  int slot = atomicAdd(&cursor[dst], 1);
  if (slot < DEG_CAP) slots[(size_t)dst * DEG_CAP + slot] = e;
}

// ---------- main gather: msg aggregation + root + bias, BN stats ----------
__global__ __launch_bounds__(256, 2) void k_gather(
    const float* __restrict__ x, const int* __restrict__ ei,
    const float* __restrict__ he, const int* __restrict__ cursor,
    const int* __restrict__ slots, const float* __restrict__ w_e2,
    const float* __restrict__ b_e2, const float* __restrict__ root,
    const float* __restrict__ conv_bias, float* __restrict__ hout,
    float* __restrict__ stats, int N, int E) {
  int lane = threadIdx.x & 63;
  int wid = blockIdx.x * (blockDim.x >> 6) + (threadIdx.x >> 6);
  int nw = gridDim.x * (blockDim.x >> 6);

  // per-lane (h = lane) constant weights in registers
  float w2r[16][8];
#pragma unroll
  for (int k = 0; k < 16; ++k)
#pragma unroll
    for (int f = 0; f < 8; ++f) w2r[k][f] = w_e2[k * 512 + f * 64 + lane];
  float b2r[8], rootr[8];
#pragma unroll
  for (int f = 0; f < 8; ++f) b2r[f] = b_e2[f * 64 + lane];
#pragma unroll
  for (int f = 0; f < 8; ++f) rootr[f] = root[f * 64 + lane];
  float cb = conv_bias[lane];

  float bnsum = 0.f, bnsq = 0.f;

  for (int n = wid; n < N; n += nw) {
    int d = cursor[n];          // wave-uniform
    int dc = min(d, DEG_CAP);
    float acc = 0.f;
    int eid_l = (lane < dc) ? slots[(size_t)n * DEG_CAP + lane] : 0;
    if (dc > 0) {
      int eid = rfl(__shfl(eid_l, 0));
      int s = rfl(ei[eid]);
      float hv[16], xv[8];
      {
        const float* hep = he + (size_t)eid * 16;
        const float* xp = x + (size_t)s * 8;
#pragma unroll
        for (int k = 0; k < 16; ++k) hv[k] = hep[k];
#pragma unroll
        for (int f = 0; f < 8; ++f) xv[f] = xp[f];
      }
      for (int i = 0; i < dc; ++i) {
        float hv2[16], xv2[8];
        if (i + 1 < dc) {  // prefetch next edge (uniform scalar loads)
          int eid2 = rfl(__shfl(eid_l, i + 1));
          int s2 = rfl(ei[eid2]);
          const float* hep2 = he + (size_t)eid2 * 16;
          const float* xp2 = x + (size_t)s2 * 8;
#pragma unroll
          for (int k = 0; k < 16; ++k) hv2[k] = hep2[k];
#pragma unroll
          for (int f = 0; f < 8; ++f) xv2[f] = xp2[f];
        }
        float p[8];
#pragma unroll
        for (int f = 0; f < 8; ++f) p[f] = b2r[f];
#pragma unroll
        for (int k = 0; k < 16; ++k) {
          float hk = hv[k];
#pragma unroll
          for (int f = 0; f < 8; ++f) p[f] = fmaf(hk, w2r[k][f], p[f]);
        }
        float m = 0.f;
#pragma unroll
        for (int f = 0; f < 8; ++f) m = fmaf(p[f], xv[f], m);
        acc += m;
        if (i + 1 < dc) {
#pragma unroll
          for (int k = 0; k < 16; ++k) hv[k] = hv2[k];
#pragma unroll
          for (int f = 0; f < 8; ++f) xv[f] = xv2[f];
        }
      }
    }
    float hval = cb + acc / (float)max(d, 1);
    const float* xn = x + (size_t)n * 8;
#pragma unroll
    for (int f = 0; f < 8; ++f) hval = fmaf(xn[f], rootr[f], hval);
    hout[(size_t)n * 64 + lane] = hval;
    bnsum += hval;
    bnsq += hval * hval;
  }
  atomicAdd(&stats[lane], bnsum);
  atomicAdd(&stats[64 + lane], bnsq);
}

// ---------- BN+ReLU + per-graph pooling (batch_index sorted -> chunked) ----------
__global__ void k_bnpool(const float* __restrict__ hbuf, const float* __restrict__ stats,
                         const int* __restrict__ batch, const float* __restrict__ gamma,
                         const float* __restrict__ beta, float* __restrict__ gsum,
                         unsigned int* __restrict__ gmax, int* __restrict__ gcnt, int N) {
  int lane = threadIdx.x & 63;
  int wid = blockIdx.x * (blockDim.x >> 6) + (threadIdx.x >> 6);
  int nw = gridDim.x * (blockDim.x >> 6);
  float m = stats[lane] / (float)N;
  float var = stats[64 + lane] / (float)N - m * m;
  float rs = rsqrtf(var + 1e-5f);
  float ga = gamma[lane], be = beta[lane];
  int per = (N + nw - 1) / nw;
  int n0 = wid * per;
  int n1 = min(N, n0 + per);
  int cur = -1, cnt = 0;
  float s = 0.f, mx = 0.f;
  for (int n = n0; n < n1; ++n) {
    int g = batch[n];  // wave-uniform, sorted
    float v = hbuf[(size_t)n * 64 + lane];
    float y = fmaxf(fmaf((v - m) * rs, ga, be), 0.f);
    if (g != cur) {
      if (cur >= 0) {
        atomicAdd(&gsum[cur * 64 + lane], s);
        atomicMax(&gmax[cur * 64 + lane], __float_as_uint(mx));
        if (lane == 0) atomicAdd(&gcnt[cur], cnt);
      }
      cur = g; s = 0.f; mx = 0.f; cnt = 0;
    }
    s += y; mx = fmaxf(mx, y); ++cnt;
  }
  if (cur >= 0) {
    atomicAdd(&gsum[cur * 64 + lane], s);
    atomicMax(&gmax[cur * 64 + lane], __float_as_uint(mx));
    if (lane == 0) atomicAdd(&gcnt[cur], cnt);
  }
}

// ---------- assemble g = [gmean | gmax]  (64 x 128) ----------
__global__ void k_buildg(const float* __restrict__ gsum, const unsigned int* __restrict__ gmax,
                         const int* __restrict__ gcnt, float* __restrict__ g) {
  int t = blockIdx.x * blockDim.x + threadIdx.x;
  if (t >= 64 * 128) return;
  int r = t >> 7, c = t & 127;
  float cntf = (float)gcnt[r];
  float v;
  if (c < 64) v = gsum[r * 64 + c] / fmaxf(cntf, 1.f);
  else v = __uint_as_float(gmax[r * 64 + (c - 64)]);
  g[t] = v;
}

// ---------- head layer: out = relu(bn(in @ W + b)); wave = one column ----------
__global__ void k_head(const float* __restrict__ in, const float* __restrict__ W,
                       const float* __restrict__ b, const float* __restrict__ gamma,
                       const float* __restrict__ beta, float* __restrict__ out,
                       int Kin, int Kout) {
  int lane = threadIdx.x & 63;  // row (graph)
  int col = blockIdx.x * (blockDim.x >> 6) + (threadIdx.x >> 6);
  if (col >= Kout) return;
  const float4* ir = reinterpret_cast<const float4*>(in + (size_t)lane * Kin);
  float a = b[col];
  for (int k4 = 0; k4 < (Kin >> 2); ++k4) {
    float4 v = ir[k4];
    int k = k4 << 2;
    a = fmaf(v.x, W[(size_t)k * Kout + col], a);
    a = fmaf(v.y, W[(size_t)(k + 1) * Kout + col], a);
    a = fmaf(v.z, W[(size_t)(k + 2) * Kout + col], a);
    a = fmaf(v.w, W[(size_t)(k + 3) * Kout + col], a);
  }
  float sv = a, ss = a * a;
#pragma unroll
  for (int off = 32; off > 0; off >>= 1) {
    sv += __shfl_xor(sv, off);
    ss += __shfl_xor(ss, off);
  }
  float m = sv * (1.f / 64.f);
  float var = ss * (1.f / 64.f) - m * m;
  float y = fmaxf(fmaf((a - m) * rsqrtf(var + 1e-5f), gamma[col], beta[col]), 0.f);
  out[(size_t)lane * Kout + col] = y;
}

// ---------- final linear: [64,64] @ [64,10] + bout ----------
__global__ void k_out(const float* __restrict__ in, const float* __restrict__ W,
                      const float* __restrict__ b, float* __restrict__ out) {
  int t = threadIdx.x;
  if (t >= 640) return;
  int r = t / 10, c = t % 10;
  float a = b[c];
#pragma unroll
  for (int k = 0; k < 64; ++k) a = fmaf(in[r * 64 + k], W[k * 10 + c], a);
  out[t] = a;
}

extern "C" void kernel_launch(void* const* d_in, const int* in_sizes, int n_in,
                              void* d_out, int out_size, void* d_ws, size_t ws_size,
                              hipStream_t stream) {
  const float* x = (const float*)d_in[0];
  const int* ei = (const int*)d_in[1];
  const float* ea = (const float*)d_in[2];
  const int* batch = (const int*)d_in[3];
  const float* w_e1 = (const float*)d_in[4];
  const float* b_e1 = (const float*)d_in[5];
  const float* w_e2 = (const float*)d_in[6];
  const float* b_e2 = (const float*)d_in[7];
  const float* root = (const float*)d_in[8];
  const float* conv_bias = (const float*)d_in[9];
  const float* g_bnc = (const float*)d_in[10];
  const float* b_bnc = (const float*)d_in[11];
  const float* w1 = (const float*)d_in[12];
  const float* b1 = (const float*)d_in[13];
  const float* g1 = (const float*)d_in[14];
  const float* be1 = (const float*)d_in[15];
  const float* w2 = (const float*)d_in[16];
  const float* b2 = (const float*)d_in[17];
  const float* g2 = (const float*)d_in[18];
  const float* be2 = (const float*)d_in[19];
  const float* w3 = (const float*)d_in[20];
  const float* b3 = (const float*)d_in[21];
  const float* g3 = (const float*)d_in[22];
  const float* be3 = (const float*)d_in[23];
  const float* wout = (const float*)d_in[24];
  const float* bout = (const float*)d_in[25];

  int N = in_sizes[0] / 8;
  int E = in_sizes[1] / 2;

  char* wsb = (char*)d_ws;
  size_t off = 0;
  auto alloc = [&](size_t bytes) -> void* {
    void* p = wsb + off;
    off += (bytes + 255) & ~(size_t)255;
    return p;
  };
  float* he = (float*)alloc((size_t)E * 16 * 4);          // 32 MB
  int* cursor = (int*)alloc((size_t)N * 4);               // 0.2 MB
  int* slots = (int*)alloc((size_t)N * DEG_CAP * 4);      // 12.8 MB
  float* hbuf = (float*)alloc((size_t)N * 64 * 4);        // 12.8 MB
  float* zblk = (float*)alloc(8384 * 4);                  // stats+gsum+gmax+gcnt
  float* stats = zblk;                                    // 128
  float* gsum = zblk + 128;                               // 4096
  unsigned int* gmax = (unsigned int*)(zblk + 128 + 4096);// 4096
  int* gcnt = (int*)(zblk + 128 + 8192);                  // 64
  float* g = (float*)alloc(64 * 128 * 4);
  float* l1 = (float*)alloc(64 * 256 * 4);
  float* l2 = (float*)alloc(64 * 128 * 4);
  float* l3 = (float*)alloc(64 * 64 * 4);

  hipMemsetAsync(cursor, 0, (size_t)N * 4, stream);
  hipMemsetAsync(zblk, 0, 8384 * 4, stream);

  const int tb = 256;
  k_he<<<(E + tb - 1) / tb, tb, 0, stream>>>(ea, w_e1, b_e1, he, E);
  k_fill<<<(E + tb - 1) / tb, tb, 0, stream>>>(ei, cursor, slots, E);
  k_gather<<<512, 256, 0, stream>>>(x, ei, he, cursor, slots, w_e2, b_e2, root,
                                    conv_bias, hbuf, stats, N, E);
  k_bnpool<<<256, 256, 0, stream>>>(hbuf, stats, batch, g_bnc, b_bnc, gsum, gmax, gcnt, N);
  k_buildg<<<32, 256, 0, stream>>>(gsum, gmax, gcnt, g);
  k_head<<<64, 256, 0, stream>>>(g, w1, b1, g1, be1, l1, 128, 256);
  k_head<<<32, 256, 0, stream>>>(l1, w2, b2, g2, be2, l2, 256, 128);
  k_head<<<16, 256, 0, stream>>>(l2, w3, b3, g3, be3, l3, 128, 64);
  k_out<<<1, 640, 0, stream>>>(l3, wout, bout, (float*)d_out);
}